// Round 1
// baseline (120.691 us; speedup 1.0000x reference)
//
#include <hip/hip_runtime.h>
#include <math.h>

// Filtered Back Projection, B=2, A=181, L=512, P=1024.
// ws layout (floats):
//   [0,1024)        filt
//   [1024,2048)     hr  (real impulse response of the filter)
//   [2048,2048+181) cth = cos(angle + pi/2)
//   [2304,2304+181) sth = sin(angle + pi/2)
//   [4096, 4096+2*181*512)  sino_f planar: [b][a][pos]
#define OFF_HR   1024
#define OFF_CTH  2048
#define OFF_STH  2304
#define OFF_SF   4096
#define PLANE    92672      // 181*512
#define TWO_PI   6.283185307179586

// ---------------- filter spectrum: filt[k] = ramp[k] * hann_shift[k] -------
__global__ __launch_bounds__(64) void k_filt(const float* __restrict__ angles,
                                             float* __restrict__ ws) {
  const int k = blockIdx.x;     // 0..1023
  const int t = threadIdx.x;    // 0..63
  double acc = 0.0;
  // ramp[k] = 2*Re(fft(f))[k] = 0.5 + 2*sum_{odd j} f[j]*cos(2*pi*j*k/1024)
  for (int tt = t; tt < 512; tt += 64) {
    int jj = 2 * tt + 1;
    int n = (tt < 256) ? jj : (1023 - 2 * tt);
    double pin = 3.14159265358979323846 * (double)n;
    int r = (jj * k) & 1023;                       // exact phase reduction
    acc += (-1.0 / (pin * pin)) * cos((double)r * (TWO_PI / 1024.0));
  }
#pragma unroll
  for (int o = 32; o; o >>= 1) acc += __shfl_down(acc, o, 64);
  if (t == 0) {
    double ramp = 0.5 + 2.0 * acc;
    int ks = (k + 512) & 1023;                     // fftshift
    double hann = 0.5 - 0.5 * cos(TWO_PI * (double)ks / 1023.0);  // np.hanning
    ws[k] = (float)(ramp * hann);
  }
  if (t == 1 && k < 181) {                         // angle trig, th = a + pi/2
    float th = angles[k] + 1.5707963267948966f;
    ws[OFF_CTH + k] = cosf(th);
    ws[OFF_STH + k] = sinf(th);
  }
}

// ---------------- hr[m] = (1/P) * sum_k filt[k] * cos(2*pi*k*m/P) ----------
__global__ __launch_bounds__(64) void k_hr(float* __restrict__ ws) {
  const int m = blockIdx.x;     // 0..1023
  const int t = threadIdx.x;
  double acc = 0.0;
  for (int k = t; k < 1024; k += 64) {
    int r = (k * m) & 1023;
    acc += (double)ws[k] * cos((double)r * (TWO_PI / 1024.0));
  }
#pragma unroll
  for (int o = 32; o; o >>= 1) acc += __shfl_down(acc, o, 64);
  if (t == 0) ws[OFF_HR + m] = (float)(acc * (1.0 / 1024.0));
}

// ---------------- row-wise circular convolution with hr --------------------
// One block per (b,a) row. 64 threads x 8 outputs. j unrolled by 8:
// per step 6 ds_read_b128 feed 64 FMAs.
__global__ __launch_bounds__(64) void k_conv(const float* __restrict__ sino,
                                             float* __restrict__ ws) {
  __shared__ float s_s[512];
  __shared__ float s_hr[1024];
  const int t = threadIdx.x;
  const int row = blockIdx.x;       // 0..361 == b*181 + a
  const float4* src4 = (const float4*)(sino + (size_t)row * 512);
  float4* ss4 = (float4*)s_s;
  ss4[t] = src4[t];
  ss4[t + 64] = src4[t + 64];
  const float4* hr4 = (const float4*)(ws + OFF_HR);
  float4* sh4 = (float4*)s_hr;
#pragma unroll
  for (int q = 0; q < 4; q++) sh4[t + 64 * q] = hr4[t + 64 * q];
  __syncthreads();

  const int base = t * 8;           // output positions base..base+7
  float acc[8] = {0.f, 0.f, 0.f, 0.f, 0.f, 0.f, 0.f, 0.f};
  const float4* SH = (const float4*)s_hr;
  const float4* SS = (const float4*)s_s;
  for (int j8 = 0; j8 < 512; j8 += 8) {
    float4 sva = SS[j8 >> 2];
    float4 svb = SS[(j8 >> 2) + 1];
    int w = base - j8;
    float4 h0 = SH[((w - 8) & 1023) >> 2];
    float4 h1 = SH[((w - 4) & 1023) >> 2];
    float4 h2 = SH[(w & 1023) >> 2];
    float4 h3 = SH[((w + 4) & 1023) >> 2];
    float qq[16] = {h0.x, h0.y, h0.z, h0.w, h1.x, h1.y, h1.z, h1.w,
                    h2.x, h2.y, h2.z, h2.w, h3.x, h3.y, h3.z, h3.w};
    float sv[8] = {sva.x, sva.y, sva.z, sva.w, svb.x, svb.y, svb.z, svb.w};
#pragma unroll
    for (int jj = 0; jj < 8; jj++)
#pragma unroll
      for (int m = 0; m < 8; m++)
        acc[m] = fmaf(sv[jj], qq[8 + m - jj], acc[m]);   // hr[(i-j)&1023]
  }
  float* dst = ws + OFF_SF + (size_t)row * 512 + base;
  ((float4*)dst)[0] = make_float4(acc[0], acc[1], acc[2], acc[3]);
  ((float4*)dst)[1] = make_float4(acc[4], acc[5], acc[6], acc[7]);
}

// ---------------- backprojection -------------------------------------------
// Block = output row i (512 blocks x 512 threads, thread = column j, both
// images). Angle rows staged in LDS in chunks of 16, interleaved {img0,img1}
// per position so each lerp needs two 8B-aligned ds_read_b64 at one address.
#define CHUNK 16
__global__ __launch_bounds__(512) void k_bp(const float* __restrict__ ws,
                                            const int* __restrict__ circ,
                                            float* __restrict__ out) {
  __shared__ float srowf[CHUNK * 1024];   // 64 KB: [r][pos][img]
  const int j = threadIdx.x;
  const int i = blockIdx.x;
  const float xc = (float)(i - 256);
  const float yc = (float)(j - 256);
  const float* __restrict__ cth = ws + OFF_CTH;
  const float* __restrict__ sth = ws + OFF_STH;
  const float* __restrict__ P0 = ws + OFF_SF;
  const float* __restrict__ P1 = ws + OFF_SF + PLANE;
  float acc0 = 0.f, acc1 = 0.f;

  for (int a0 = 0; a0 < 181; a0 += CHUNK) {
    const int nv = min(CHUNK, 181 - a0);
    __syncthreads();
    // stage nv rows, de-interleaving the two image planes into float2 entries
    for (int e = j; e < nv * 128; e += 512) {
      int r = e >> 7;
      int p = (e & 127) << 2;
      size_t g = (size_t)(a0 + r) * 512 + p;
      float4 v0 = *(const float4*)(P0 + g);
      float4 v1 = *(const float4*)(P1 + g);
      float4* d = (float4*)&srowf[r * 1024 + p * 2];
      d[0] = make_float4(v0.x, v1.x, v0.y, v1.y);
      d[1] = make_float4(v0.z, v1.z, v0.w, v1.w);
    }
    __syncthreads();
    for (int r = 0; r < nv; r++) {
      const int a = a0 + r;
      const float c = cth[a];          // uniform -> scalar loads
      const float s = sth[a];
      float u = fmaf(xc, c, fmaf(yc, s, 255.5f));
      float fl = floorf(u);
      float fr = u - fl;
      int i0 = (int)fl;
      float w0 = ((unsigned)i0 < 512u) ? (1.0f - fr) : 0.0f;
      float w1 = ((unsigned)(i0 + 1) < 512u) ? fr : 0.0f;
      int b = min(max(i0, 0), 510);
      int off = i0 - b;                // -1, 0, +1 (or far out: weights are 0)
      const float2* rowp = (const float2*)&srowf[r * 1024];
      float2 rA = rowp[b];
      float2 rB = rowp[b + 1];
      float g00 = (off == 1) ? rB.x : rA.x;   // img0 tap at i0 (clipped)
      float g10 = (off == 1) ? rB.y : rA.y;   // img1 tap at i0
      float g01 = (off == -1) ? rA.x : rB.x;  // img0 tap at i0+1 (clipped)
      float g11 = (off == -1) ? rA.y : rB.y;  // img1 tap at i0+1
      acc0 = fmaf(w0, g00, fmaf(w1, g01, acc0));
      acc1 = fmaf(w0, g10, fmaf(w1, g11, acc1));
    }
  }
  const int dx = j - 256, dy = i - 256;
  const bool msk = (circ[0] != 0) && (dx * dx + dy * dy > 65536);
  const size_t o = (size_t)i * 512 + j;
  out[o] = msk ? 0.f : acc0;
  out[262144 + o] = msk ? 0.f : acc1;
}

extern "C" void kernel_launch(void* const* d_in, const int* in_sizes, int n_in,
                              void* d_out, int out_size, void* d_ws, size_t ws_size,
                              hipStream_t stream) {
  const float* sino = (const float*)d_in[0];    // (2,181,512) f32
  const float* angles = (const float*)d_in[1];  // (181,) f32
  const int* circ = (const int*)d_in[2];        // scalar int
  float* ws = (float*)d_ws;                     // needs ~758 KB
  float* out = (float*)d_out;                   // (2,512,512) f32

  hipLaunchKernelGGL(k_filt, dim3(1024), dim3(64), 0, stream, angles, ws);
  hipLaunchKernelGGL(k_hr,   dim3(1024), dim3(64), 0, stream, ws);
  hipLaunchKernelGGL(k_conv, dim3(362),  dim3(64), 0, stream, sino, ws);
  hipLaunchKernelGGL(k_bp,   dim3(512),  dim3(512), 0, stream, ws, circ, out);
}